// Round 3
// baseline (1182.472 us; speedup 1.0000x reference)
//
#include <hip/hip_runtime.h>

// approxmatch EMD (Fan et al.) on MI355X, B=4, N=M=4096, layout (B,3,N).
// Round 3: packed-fp32 (float2 -> v_pk_*) inner loops, 2 cols/lane;
// exp-chaining: exp2(ls2*d) = (exp2(ls2n*d))^4 since levels are powers of 4
// -> cost_fused needs only 2 trans/pair (exp of NEXT level + sqrt).
// pass3(t) fused with pass1(t+1); level-0 sweep specialcased (e == 1).

#define NPTS 4096
#define BATCH 4
#define EMD_EPS 1e-9f
#define TILE 1024        // columns staged per LDS stage
#define RPW 4            // rows per wave, in registers
#define THREADS 256      // 4 waves
#define RPB 16           // rows per block = 4 waves * RPW
#define NBLK (NPTS / RPB)  // 256 row-blocks per batch

__device__ __forceinline__ float fexp2(float x) {
#if __has_builtin(__builtin_amdgcn_exp2f)
    return __builtin_amdgcn_exp2f(x);
#else
    return exp2f(x);
#endif
}
__device__ __forceinline__ float fsqrt(float x) {
#if __has_builtin(__builtin_amdgcn_sqrtf)
    return __builtin_amdgcn_sqrtf(x);
#else
    return __sqrtf(x);
#endif
}

__device__ __forceinline__ float wave_reduce(float v) {
    v += __shfl_xor(v, 32);
    v += __shfl_xor(v, 16);
    v += __shfl_xor(v, 8);
    v += __shfl_xor(v, 4);
    v += __shfl_xor(v, 2);
    v += __shfl_xor(v, 1);
    return v;
}

// ---------------------------------------------------------------- init
__global__ void k_init(float* __restrict__ remainL, float* __restrict__ remainR,
                       float* __restrict__ cost_part) {
    int i = blockIdx.x * blockDim.x + threadIdx.x;
    if (i < BATCH * NPTS) {
        remainL[i] = 1.0f;   // multiL = 1 (n == m)
        remainR[i] = 1.0f;
    }
    if (i < BATCH * NBLK) cost_part[i] = 0.0f;
}

// ---------------------------------------------------------------- pass 1 (sweep 0 only)
// remainR == 1 here, so ratioL_k = 1 / (EPS + sum_l exp2(ls2*d))
__global__ __launch_bounds__(THREADS, 4) void k_ratioL0(
        const float* __restrict__ xyz1, const float* __restrict__ xyz2,
        float* __restrict__ ratioL, float ls2) {
    const int b = blockIdx.y;
    const int tid = threadIdx.x;
    const int wave = tid >> 6;
    const int lane = tid & 63;
    const int row0 = blockIdx.x * RPB + wave * RPW;

    const float* x1 = xyz1 + b * 3 * NPTS;
    const float* x2 = xyz2 + b * 3 * NPTS;
    const float2* x2x = (const float2*)(x2);
    const float2* x2y = (const float2*)(x2 + NPTS);
    const float2* x2z = (const float2*)(x2 + 2 * NPTS);

    float px[RPW], py[RPW], pz[RPW];
    float2 acc[RPW];
#pragma unroll
    for (int r = 0; r < RPW; ++r) {
        px[r] = x1[row0 + r];
        py[r] = x1[NPTS + row0 + r];
        pz[r] = x1[2 * NPTS + row0 + r];
        acc[r] = make_float2(0.0f, 0.0f);
    }
    __shared__ float4 sA[TILE / 2];   // x0,x1,y0,y1
    __shared__ float2 sZ[TILE / 2];   // z0,z1

    for (int c0 = 0; c0 < NPTS; c0 += TILE) {
        __syncthreads();
        for (int i = tid; i < TILE / 2; i += THREADS) {
            int e = c0 / 2 + i;
            float2 xx = x2x[e], yy = x2y[e];
            sA[i] = make_float4(xx.x, xx.y, yy.x, yy.y);
            sZ[i] = x2z[e];
        }
        __syncthreads();
#pragma unroll
        for (int j = 0; j < TILE / 128; ++j) {
            float4 a = sA[lane + 64 * j];
            float2 z = sZ[lane + 64 * j];
#pragma unroll
            for (int r = 0; r < RPW; ++r) {
                float dx0 = px[r] - a.x, dx1 = px[r] - a.y;
                float dy0 = py[r] - a.z, dy1 = py[r] - a.w;
                float dz0 = pz[r] - z.x, dz1 = pz[r] - z.y;
                float d0 = fmaf(dx0, dx0, fmaf(dy0, dy0, dz0 * dz0));
                float d1 = fmaf(dx1, dx1, fmaf(dy1, dy1, dz1 * dz1));
                acc[r].x += fexp2(ls2 * d0);
                acc[r].y += fexp2(ls2 * d1);
            }
        }
    }
    if (true) {
#pragma unroll
        for (int r = 0; r < RPW; ++r) {
            float s = wave_reduce(acc[r].x + acc[r].y);
            if (lane == 0)
                ratioL[b * NPTS + row0 + r] = 1.0f / (EMD_EPS + s);
        }
    }
}

// ---------------------------------------------------------------- pass 2
// per column l: s = sum_k e*ratioL_k ; sumr = remainR*s ;
// ratioR = min(remainR/(sumr+EPS),1)*remainR ; remainR = max(0, remainR-sumr)
__global__ __launch_bounds__(THREADS, 4) void k_ratioR(
        const float* __restrict__ xyz1, const float* __restrict__ xyz2,
        const float* __restrict__ ratioL, float* __restrict__ ratioR,
        float* __restrict__ remainR, float ls2) {
    const int b = blockIdx.y;
    const int tid = threadIdx.x;
    const int wave = tid >> 6;
    const int lane = tid & 63;
    const int col0 = blockIdx.x * RPB + wave * RPW;

    const float* x1 = xyz1 + b * 3 * NPTS;
    const float* x2 = xyz2 + b * 3 * NPTS;
    const float2* x1x = (const float2*)(x1);
    const float2* x1y = (const float2*)(x1 + NPTS);
    const float2* x1z = (const float2*)(x1 + 2 * NPTS);
    const float2* wLv = (const float2*)(ratioL + b * NPTS);

    float px[RPW], py[RPW], pz[RPW];
    float2 acc[RPW];
#pragma unroll
    for (int r = 0; r < RPW; ++r) {
        px[r] = x2[col0 + r];
        py[r] = x2[NPTS + col0 + r];
        pz[r] = x2[2 * NPTS + col0 + r];
        acc[r] = make_float2(0.0f, 0.0f);
    }
    __shared__ float4 sA[TILE / 2];   // x0,x1,y0,y1
    __shared__ float4 sB[TILE / 2];   // z0,z1,w0,w1

    for (int c0 = 0; c0 < NPTS; c0 += TILE) {
        __syncthreads();
        for (int i = tid; i < TILE / 2; i += THREADS) {
            int e = c0 / 2 + i;
            float2 xx = x1x[e], yy = x1y[e], zz = x1z[e], ww = wLv[e];
            sA[i] = make_float4(xx.x, xx.y, yy.x, yy.y);
            sB[i] = make_float4(zz.x, zz.y, ww.x, ww.y);
        }
        __syncthreads();
#pragma unroll
        for (int j = 0; j < TILE / 128; ++j) {
            float4 a = sA[lane + 64 * j];
            float4 bq = sB[lane + 64 * j];
#pragma unroll
            for (int r = 0; r < RPW; ++r) {
                float dx0 = px[r] - a.x, dx1 = px[r] - a.y;
                float dy0 = py[r] - a.z, dy1 = py[r] - a.w;
                float dz0 = pz[r] - bq.x, dz1 = pz[r] - bq.y;
                float d0 = fmaf(dx0, dx0, fmaf(dy0, dy0, dz0 * dz0));
                float d1 = fmaf(dx1, dx1, fmaf(dy1, dy1, dz1 * dz1));
                acc[r].x = fmaf(fexp2(ls2 * d0), bq.z, acc[r].x);
                acc[r].y = fmaf(fexp2(ls2 * d1), bq.w, acc[r].y);
            }
        }
    }
#pragma unroll
    for (int r = 0; r < RPW; ++r) {
        float s = wave_reduce(acc[r].x + acc[r].y);
        if (lane == 0) {
            int idx = b * NPTS + col0 + r;
            float rv = remainR[idx];
            float sumr = rv * s;
            float cons = fminf(rv / (sumr + EMD_EPS), 1.0f);
            ratioR[idx] = cons * rv;
            remainR[idx] = fmaxf(0.0f, rv - sumr);
        }
    }
}

// ---------------------------------------------------------------- pass 3(t) + pass 1(t+1) fused
// e2 = exp2(ls2n*d)  (next level's e, ls2 == 4*ls2n exactly for t=0..7)
// er = e2^4 * ratioR (SQ path)  or  er = exp2(ls2*d)*ratioR (t=8, ls2n==0)
// acc_a = sum er ; acc_c = sum er*sqrt(d) ; acc_s = sum e2*remainR
template <bool SQ>
__global__ __launch_bounds__(THREADS, 4) void k_cost_fused(
        const float* __restrict__ xyz1, const float* __restrict__ xyz2,
        float* __restrict__ ratioL, const float* __restrict__ ratioR,
        float* __restrict__ remainL, const float* __restrict__ remainR,
        float* __restrict__ cost_part, float ls2, float ls2n) {
    const int b = blockIdx.y;
    const int tid = threadIdx.x;
    const int wave = tid >> 6;
    const int lane = tid & 63;
    const int row0 = blockIdx.x * RPB + wave * RPW;

    const float* x1 = xyz1 + b * 3 * NPTS;
    const float* x2 = xyz2 + b * 3 * NPTS;
    const float2* x2x = (const float2*)(x2);
    const float2* x2y = (const float2*)(x2 + NPTS);
    const float2* x2z = (const float2*)(x2 + 2 * NPTS);
    const float2* wRv = (const float2*)(ratioR + b * NPTS);
    const float2* w2v = (const float2*)(remainR + b * NPTS);

    float px[RPW], py[RPW], pz[RPW];
    float2 acc_a[RPW], acc_c[RPW], acc_s[RPW];
#pragma unroll
    for (int r = 0; r < RPW; ++r) {
        px[r] = x1[row0 + r];
        py[r] = x1[NPTS + row0 + r];
        pz[r] = x1[2 * NPTS + row0 + r];
        acc_a[r] = make_float2(0.0f, 0.0f);
        acc_c[r] = make_float2(0.0f, 0.0f);
        acc_s[r] = make_float2(0.0f, 0.0f);
    }
    __shared__ float4 sA[TILE / 2];   // x0,x1,y0,y1
    __shared__ float4 sB[TILE / 2];   // z0,z1,wR0,wR1
    __shared__ float2 sC[TILE / 2];   // w20,w21
    __shared__ float s_cost[THREADS / 64];

    for (int c0 = 0; c0 < NPTS; c0 += TILE) {
        __syncthreads();
        for (int i = tid; i < TILE / 2; i += THREADS) {
            int e = c0 / 2 + i;
            float2 xx = x2x[e], yy = x2y[e], zz = x2z[e], wr = wRv[e];
            sA[i] = make_float4(xx.x, xx.y, yy.x, yy.y);
            sB[i] = make_float4(zz.x, zz.y, wr.x, wr.y);
            sC[i] = w2v[e];
        }
        __syncthreads();
#pragma unroll
        for (int j = 0; j < TILE / 128; ++j) {
            float4 a = sA[lane + 64 * j];
            float4 bq = sB[lane + 64 * j];
            float2 c = sC[lane + 64 * j];
#pragma unroll
            for (int r = 0; r < RPW; ++r) {
                float dx0 = px[r] - a.x, dx1 = px[r] - a.y;
                float dy0 = py[r] - a.z, dy1 = py[r] - a.w;
                float dz0 = pz[r] - bq.x, dz1 = pz[r] - bq.y;
                float d0 = fmaf(dx0, dx0, fmaf(dy0, dy0, dz0 * dz0));
                float d1 = fmaf(dx1, dx1, fmaf(dy1, dy1, dz1 * dz1));
                float er0, er1;
                if (SQ) {
                    float e20 = fexp2(ls2n * d0);
                    float e21 = fexp2(ls2n * d1);
                    acc_s[r].x = fmaf(e20, c.x, acc_s[r].x);
                    acc_s[r].y = fmaf(e21, c.y, acc_s[r].y);
                    float e40 = e20 * e20, e41 = e21 * e21;
                    er0 = (e40 * e40) * bq.z;
                    er1 = (e41 * e41) * bq.w;
                } else {
                    // only used for t=8 where ls2n == 0 -> e2 == 1
                    er0 = fexp2(ls2 * d0) * bq.z;
                    er1 = fexp2(ls2 * d1) * bq.w;
                    acc_s[r].x += c.x;
                    acc_s[r].y += c.y;
                }
                acc_a[r].x += er0;
                acc_a[r].y += er1;
                acc_c[r].x = fmaf(er0, fsqrt(d0), acc_c[r].x);
                acc_c[r].y = fmaf(er1, fsqrt(d1), acc_c[r].y);
            }
        }
    }
    float wcost = 0.0f;
#pragma unroll
    for (int r = 0; r < RPW; ++r) {
        float sa = wave_reduce(acc_a[r].x + acc_a[r].y);
        float sc = wave_reduce(acc_c[r].x + acc_c[r].y);
        float ss = wave_reduce(acc_s[r].x + acc_s[r].y);
        if (lane == 0) {
            int idx = b * NPTS + row0 + r;
            float rl = ratioL[idx];
            float rem = fmaxf(0.0f, remainL[idx] - rl * sa);
            remainL[idx] = rem;
            ratioL[idx] = rem / (EMD_EPS + ss);   // next sweep's ratioL
            wcost = fmaf(rl, sc, wcost);
        }
    }
    if (lane == 0) s_cost[wave] = wcost;
    __syncthreads();
    if (tid == 0) {
        float t = s_cost[0] + s_cost[1] + s_cost[2] + s_cost[3];
        cost_part[b * NBLK + blockIdx.x] += t;   // exclusive owner
    }
}

// ---------------------------------------------------------------- level-0 small kernels
__global__ void k_sum_ratioL(const float* __restrict__ ratioL, float* __restrict__ S_L) {
    const int b = blockIdx.x;
    const int tid = threadIdx.x;
    float s = 0.0f;
    for (int i = tid; i < NPTS; i += 256) s += ratioL[b * NPTS + i];
    s = wave_reduce(s);
    __shared__ float sw[4];
    if ((tid & 63) == 0) sw[tid >> 6] = s;
    __syncthreads();
    if (tid == 0) S_L[b] = sw[0] + sw[1] + sw[2] + sw[3];
}

__global__ void k_ratioR_l0(const float* __restrict__ remainR,
                            const float* __restrict__ S_L,
                            float* __restrict__ ratioR) {
    int i = blockIdx.x * blockDim.x + threadIdx.x;
    int b = i >> 12;                       // NPTS = 4096
    float rv = remainR[i];
    float sumr = rv * S_L[b];
    float cons = fminf(rv / (sumr + EMD_EPS), 1.0f);
    ratioR[i] = cons * rv;
}

// level 0 cost pass: e == 1 -> c_k = sum_l ratioR_l*sqrt(d); cost += ratioL_k*c_k
__global__ __launch_bounds__(THREADS, 4) void k_cost_l0(
        const float* __restrict__ xyz1, const float* __restrict__ xyz2,
        const float* __restrict__ ratioL, const float* __restrict__ ratioR,
        float* __restrict__ cost_part) {
    const int b = blockIdx.y;
    const int tid = threadIdx.x;
    const int wave = tid >> 6;
    const int lane = tid & 63;
    const int row0 = blockIdx.x * RPB + wave * RPW;

    const float* x1 = xyz1 + b * 3 * NPTS;
    const float* x2 = xyz2 + b * 3 * NPTS;
    const float2* x2x = (const float2*)(x2);
    const float2* x2y = (const float2*)(x2 + NPTS);
    const float2* x2z = (const float2*)(x2 + 2 * NPTS);
    const float2* wRv = (const float2*)(ratioR + b * NPTS);

    float px[RPW], py[RPW], pz[RPW];
    float2 acc_c[RPW];
#pragma unroll
    for (int r = 0; r < RPW; ++r) {
        px[r] = x1[row0 + r];
        py[r] = x1[NPTS + row0 + r];
        pz[r] = x1[2 * NPTS + row0 + r];
        acc_c[r] = make_float2(0.0f, 0.0f);
    }
    __shared__ float4 sA[TILE / 2];
    __shared__ float4 sB[TILE / 2];
    __shared__ float s_cost[THREADS / 64];

    for (int c0 = 0; c0 < NPTS; c0 += TILE) {
        __syncthreads();
        for (int i = tid; i < TILE / 2; i += THREADS) {
            int e = c0 / 2 + i;
            float2 xx = x2x[e], yy = x2y[e], zz = x2z[e], wr = wRv[e];
            sA[i] = make_float4(xx.x, xx.y, yy.x, yy.y);
            sB[i] = make_float4(zz.x, zz.y, wr.x, wr.y);
        }
        __syncthreads();
#pragma unroll
        for (int j = 0; j < TILE / 128; ++j) {
            float4 a = sA[lane + 64 * j];
            float4 bq = sB[lane + 64 * j];
#pragma unroll
            for (int r = 0; r < RPW; ++r) {
                float dx0 = px[r] - a.x, dx1 = px[r] - a.y;
                float dy0 = py[r] - a.z, dy1 = py[r] - a.w;
                float dz0 = pz[r] - bq.x, dz1 = pz[r] - bq.y;
                float d0 = fmaf(dx0, dx0, fmaf(dy0, dy0, dz0 * dz0));
                float d1 = fmaf(dx1, dx1, fmaf(dy1, dy1, dz1 * dz1));
                acc_c[r].x = fmaf(bq.z, fsqrt(d0), acc_c[r].x);
                acc_c[r].y = fmaf(bq.w, fsqrt(d1), acc_c[r].y);
            }
        }
    }
    float wcost = 0.0f;
#pragma unroll
    for (int r = 0; r < RPW; ++r) {
        float sc = wave_reduce(acc_c[r].x + acc_c[r].y);
        if (lane == 0)
            wcost = fmaf(ratioL[b * NPTS + row0 + r], sc, wcost);
    }
    if (lane == 0) s_cost[wave] = wcost;
    __syncthreads();
    if (tid == 0) {
        float t = s_cost[0] + s_cost[1] + s_cost[2] + s_cost[3];
        cost_part[b * NBLK + blockIdx.x] += t;
    }
}

// ---------------------------------------------------------------- finalize
__global__ void k_final(const float* __restrict__ cost_part, float* __restrict__ out) {
    const int tid = threadIdx.x;
    float s = 0.0f;
    for (int i = tid; i < BATCH * NBLK; i += 256) s += cost_part[i];
    s = wave_reduce(s);
    __shared__ float sw[4];
    if ((tid & 63) == 0) sw[tid >> 6] = s;
    __syncthreads();
    if (tid == 0) out[0] = (sw[0] + sw[1] + sw[2] + sw[3]) / ((float)NPTS * (float)BATCH);
}

extern "C" void kernel_launch(void* const* d_in, const int* in_sizes, int n_in,
                              void* d_out, int out_size, void* d_ws, size_t ws_size,
                              hipStream_t stream) {
    const float* xyz1 = (const float*)d_in[0];
    const float* xyz2 = (const float*)d_in[1];
    float* out = (float*)d_out;

    float* ws = (float*)d_ws;
    float* remainL  = ws;                      // B*N
    float* remainR  = ws + 1 * BATCH * NPTS;   // B*N
    float* ratioL   = ws + 2 * BATCH * NPTS;   // B*N
    float* ratioR   = ws + 3 * BATCH * NPTS;   // B*N
    float* cost_part = ws + 4 * BATCH * NPTS;  // B*NBLK
    float* S_L      = cost_part + BATCH * NBLK; // B

    // levels: -(4^j) for j = 7..-1, then 0; premultiplied by log2(e).
    // Consecutive levels differ by exactly 4x -> ls2[t] == 4*ls2[t+1] exactly.
    static const float levels[10] = {
        -16384.0f, -4096.0f, -1024.0f, -256.0f, -64.0f,
        -16.0f, -4.0f, -1.0f, -0.25f, 0.0f};
    float ls2[10];
    for (int t = 0; t < 10; ++t)
        ls2[t] = (float)(levels[t] * 1.4426950408889634);

    dim3 grid(NBLK, BATCH);

    k_init<<<(BATCH * NPTS + 255) / 256, 256, 0, stream>>>(remainL, remainR, cost_part);
    k_ratioL0<<<grid, THREADS, 0, stream>>>(xyz1, xyz2, ratioL, ls2[0]);
    for (int t = 0; t < 8; ++t) {
        k_ratioR<<<grid, THREADS, 0, stream>>>(xyz1, xyz2, ratioL, ratioR, remainR, ls2[t]);
        k_cost_fused<true><<<grid, THREADS, 0, stream>>>(xyz1, xyz2, ratioL, ratioR,
                                                         remainL, remainR, cost_part,
                                                         ls2[t], ls2[t + 1]);
    }
    // t = 8: next level is 0 (no 4x relation) -> direct-exp variant
    k_ratioR<<<grid, THREADS, 0, stream>>>(xyz1, xyz2, ratioL, ratioR, remainR, ls2[8]);
    k_cost_fused<false><<<grid, THREADS, 0, stream>>>(xyz1, xyz2, ratioL, ratioR,
                                                      remainL, remainR, cost_part,
                                                      ls2[8], 0.0f);
    // sweep 9 (level == 0): pass1/pass2 collapse to vector ops
    k_sum_ratioL<<<BATCH, 256, 0, stream>>>(ratioL, S_L);
    k_ratioR_l0<<<(BATCH * NPTS) / 256, 256, 0, stream>>>(remainR, S_L, ratioR);
    k_cost_l0<<<grid, THREADS, 0, stream>>>(xyz1, xyz2, ratioL, ratioR, cost_part);
    k_final<<<1, 256, 0, stream>>>(cost_part, out);
}

// Round 4
// 574.980 us; speedup vs baseline: 2.0565x; 2.0565x over previous
//
#include <hip/hip_runtime.h>

// approxmatch EMD (Fan et al.) on MI355X, B=4, N=M=4096, layout (B,3,N).
// Round 4: round-3 math (packed float2 lanes, exp-chaining: exp2(ls2*d) =
// (exp2(ls2n*d))^4 since consecutive levels differ by exactly 4x) with the
// register-pressure fix: j-loop unroll capped at 2, launch_bounds min-waves 2.
// Round-3 post-mortem: full 8x unroll + (256,4) VGPR cap 128 -> massive
// scratch spill (332 MB WRITE_SIZE/dispatch, HBM-bound at 59% peak).

#define NPTS 4096
#define BATCH 4
#define EMD_EPS 1e-9f
#define TILE 1024        // columns staged per LDS stage
#define RPW 4            // rows per wave, in registers
#define THREADS 256      // 4 waves
#define RPB 16           // rows per block = 4 waves * RPW
#define NBLK (NPTS / RPB)  // 256 row-blocks per batch

__device__ __forceinline__ float fexp2(float x) {
#if __has_builtin(__builtin_amdgcn_exp2f)
    return __builtin_amdgcn_exp2f(x);
#else
    return exp2f(x);
#endif
}
__device__ __forceinline__ float fsqrt(float x) {
#if __has_builtin(__builtin_amdgcn_sqrtf)
    return __builtin_amdgcn_sqrtf(x);
#else
    return __sqrtf(x);
#endif
}

__device__ __forceinline__ float wave_reduce(float v) {
    v += __shfl_xor(v, 32);
    v += __shfl_xor(v, 16);
    v += __shfl_xor(v, 8);
    v += __shfl_xor(v, 4);
    v += __shfl_xor(v, 2);
    v += __shfl_xor(v, 1);
    return v;
}

// ---------------------------------------------------------------- init
__global__ void k_init(float* __restrict__ remainL, float* __restrict__ remainR,
                       float* __restrict__ cost_part) {
    int i = blockIdx.x * blockDim.x + threadIdx.x;
    if (i < BATCH * NPTS) {
        remainL[i] = 1.0f;   // multiL = 1 (n == m)
        remainR[i] = 1.0f;
    }
    if (i < BATCH * NBLK) cost_part[i] = 0.0f;
}

// ---------------------------------------------------------------- pass 1 (sweep 0 only)
// remainR == 1 here, so ratioL_k = 1 / (EPS + sum_l exp2(ls2*d))
__global__ __launch_bounds__(THREADS, 2) void k_ratioL0(
        const float* __restrict__ xyz1, const float* __restrict__ xyz2,
        float* __restrict__ ratioL, float ls2) {
    const int b = blockIdx.y;
    const int tid = threadIdx.x;
    const int wave = tid >> 6;
    const int lane = tid & 63;
    const int row0 = blockIdx.x * RPB + wave * RPW;

    const float* x1 = xyz1 + b * 3 * NPTS;
    const float* x2 = xyz2 + b * 3 * NPTS;
    const float2* x2x = (const float2*)(x2);
    const float2* x2y = (const float2*)(x2 + NPTS);
    const float2* x2z = (const float2*)(x2 + 2 * NPTS);

    float px[RPW], py[RPW], pz[RPW];
    float2 acc[RPW];
#pragma unroll
    for (int r = 0; r < RPW; ++r) {
        px[r] = x1[row0 + r];
        py[r] = x1[NPTS + row0 + r];
        pz[r] = x1[2 * NPTS + row0 + r];
        acc[r] = make_float2(0.0f, 0.0f);
    }
    __shared__ float4 sA[TILE / 2];   // x0,x1,y0,y1
    __shared__ float2 sZ[TILE / 2];   // z0,z1

    for (int c0 = 0; c0 < NPTS; c0 += TILE) {
        __syncthreads();
        for (int i = tid; i < TILE / 2; i += THREADS) {
            int e = c0 / 2 + i;
            float2 xx = x2x[e], yy = x2y[e];
            sA[i] = make_float4(xx.x, xx.y, yy.x, yy.y);
            sZ[i] = x2z[e];
        }
        __syncthreads();
#pragma unroll 2
        for (int j = 0; j < TILE / 128; ++j) {
            float4 a = sA[lane + 64 * j];
            float2 z = sZ[lane + 64 * j];
#pragma unroll
            for (int r = 0; r < RPW; ++r) {
                float dx0 = px[r] - a.x, dx1 = px[r] - a.y;
                float dy0 = py[r] - a.z, dy1 = py[r] - a.w;
                float dz0 = pz[r] - z.x, dz1 = pz[r] - z.y;
                float d0 = fmaf(dx0, dx0, fmaf(dy0, dy0, dz0 * dz0));
                float d1 = fmaf(dx1, dx1, fmaf(dy1, dy1, dz1 * dz1));
                acc[r].x += fexp2(ls2 * d0);
                acc[r].y += fexp2(ls2 * d1);
            }
        }
    }
#pragma unroll
    for (int r = 0; r < RPW; ++r) {
        float s = wave_reduce(acc[r].x + acc[r].y);
        if (lane == 0)
            ratioL[b * NPTS + row0 + r] = 1.0f / (EMD_EPS + s);
    }
}

// ---------------------------------------------------------------- pass 2
// per column l: s = sum_k e*ratioL_k ; sumr = remainR*s ;
// ratioR = min(remainR/(sumr+EPS),1)*remainR ; remainR = max(0, remainR-sumr)
__global__ __launch_bounds__(THREADS, 2) void k_ratioR(
        const float* __restrict__ xyz1, const float* __restrict__ xyz2,
        const float* __restrict__ ratioL, float* __restrict__ ratioR,
        float* __restrict__ remainR, float ls2) {
    const int b = blockIdx.y;
    const int tid = threadIdx.x;
    const int wave = tid >> 6;
    const int lane = tid & 63;
    const int col0 = blockIdx.x * RPB + wave * RPW;

    const float* x1 = xyz1 + b * 3 * NPTS;
    const float* x2 = xyz2 + b * 3 * NPTS;
    const float2* x1x = (const float2*)(x1);
    const float2* x1y = (const float2*)(x1 + NPTS);
    const float2* x1z = (const float2*)(x1 + 2 * NPTS);
    const float2* wLv = (const float2*)(ratioL + b * NPTS);

    float px[RPW], py[RPW], pz[RPW];
    float2 acc[RPW];
#pragma unroll
    for (int r = 0; r < RPW; ++r) {
        px[r] = x2[col0 + r];
        py[r] = x2[NPTS + col0 + r];
        pz[r] = x2[2 * NPTS + col0 + r];
        acc[r] = make_float2(0.0f, 0.0f);
    }
    __shared__ float4 sA[TILE / 2];   // x0,x1,y0,y1
    __shared__ float4 sB[TILE / 2];   // z0,z1,w0,w1

    for (int c0 = 0; c0 < NPTS; c0 += TILE) {
        __syncthreads();
        for (int i = tid; i < TILE / 2; i += THREADS) {
            int e = c0 / 2 + i;
            float2 xx = x1x[e], yy = x1y[e], zz = x1z[e], ww = wLv[e];
            sA[i] = make_float4(xx.x, xx.y, yy.x, yy.y);
            sB[i] = make_float4(zz.x, zz.y, ww.x, ww.y);
        }
        __syncthreads();
#pragma unroll 2
        for (int j = 0; j < TILE / 128; ++j) {
            float4 a = sA[lane + 64 * j];
            float4 bq = sB[lane + 64 * j];
#pragma unroll
            for (int r = 0; r < RPW; ++r) {
                float dx0 = px[r] - a.x, dx1 = px[r] - a.y;
                float dy0 = py[r] - a.z, dy1 = py[r] - a.w;
                float dz0 = pz[r] - bq.x, dz1 = pz[r] - bq.y;
                float d0 = fmaf(dx0, dx0, fmaf(dy0, dy0, dz0 * dz0));
                float d1 = fmaf(dx1, dx1, fmaf(dy1, dy1, dz1 * dz1));
                acc[r].x = fmaf(fexp2(ls2 * d0), bq.z, acc[r].x);
                acc[r].y = fmaf(fexp2(ls2 * d1), bq.w, acc[r].y);
            }
        }
    }
#pragma unroll
    for (int r = 0; r < RPW; ++r) {
        float s = wave_reduce(acc[r].x + acc[r].y);
        if (lane == 0) {
            int idx = b * NPTS + col0 + r;
            float rv = remainR[idx];
            float sumr = rv * s;
            float cons = fminf(rv / (sumr + EMD_EPS), 1.0f);
            ratioR[idx] = cons * rv;
            remainR[idx] = fmaxf(0.0f, rv - sumr);
        }
    }
}

// ---------------------------------------------------------------- pass 3(t) + pass 1(t+1) fused
// e2 = exp2(ls2n*d)  (next level's e, ls2 == 4*ls2n exactly for t=0..7)
// er = e2^4 * ratioR (SQ path)  or  er = exp2(ls2*d)*ratioR (t=8, ls2n==0)
// acc_a = sum er ; acc_c = sum er*sqrt(d) ; acc_s = sum e2*remainR
template <bool SQ>
__global__ __launch_bounds__(THREADS, 2) void k_cost_fused(
        const float* __restrict__ xyz1, const float* __restrict__ xyz2,
        float* __restrict__ ratioL, const float* __restrict__ ratioR,
        float* __restrict__ remainL, const float* __restrict__ remainR,
        float* __restrict__ cost_part, float ls2, float ls2n) {
    const int b = blockIdx.y;
    const int tid = threadIdx.x;
    const int wave = tid >> 6;
    const int lane = tid & 63;
    const int row0 = blockIdx.x * RPB + wave * RPW;

    const float* x1 = xyz1 + b * 3 * NPTS;
    const float* x2 = xyz2 + b * 3 * NPTS;
    const float2* x2x = (const float2*)(x2);
    const float2* x2y = (const float2*)(x2 + NPTS);
    const float2* x2z = (const float2*)(x2 + 2 * NPTS);
    const float2* wRv = (const float2*)(ratioR + b * NPTS);
    const float2* w2v = (const float2*)(remainR + b * NPTS);

    float px[RPW], py[RPW], pz[RPW];
    float2 acc_a[RPW], acc_c[RPW], acc_s[RPW];
#pragma unroll
    for (int r = 0; r < RPW; ++r) {
        px[r] = x1[row0 + r];
        py[r] = x1[NPTS + row0 + r];
        pz[r] = x1[2 * NPTS + row0 + r];
        acc_a[r] = make_float2(0.0f, 0.0f);
        acc_c[r] = make_float2(0.0f, 0.0f);
        acc_s[r] = make_float2(0.0f, 0.0f);
    }
    __shared__ float4 sA[TILE / 2];   // x0,x1,y0,y1
    __shared__ float4 sB[TILE / 2];   // z0,z1,wR0,wR1
    __shared__ float2 sC[TILE / 2];   // w20,w21
    __shared__ float s_cost[THREADS / 64];

    for (int c0 = 0; c0 < NPTS; c0 += TILE) {
        __syncthreads();
        for (int i = tid; i < TILE / 2; i += THREADS) {
            int e = c0 / 2 + i;
            float2 xx = x2x[e], yy = x2y[e], zz = x2z[e], wr = wRv[e];
            sA[i] = make_float4(xx.x, xx.y, yy.x, yy.y);
            sB[i] = make_float4(zz.x, zz.y, wr.x, wr.y);
            sC[i] = w2v[e];
        }
        __syncthreads();
#pragma unroll 2
        for (int j = 0; j < TILE / 128; ++j) {
            float4 a = sA[lane + 64 * j];
            float4 bq = sB[lane + 64 * j];
            float2 c = sC[lane + 64 * j];
#pragma unroll
            for (int r = 0; r < RPW; ++r) {
                float dx0 = px[r] - a.x, dx1 = px[r] - a.y;
                float dy0 = py[r] - a.z, dy1 = py[r] - a.w;
                float dz0 = pz[r] - bq.x, dz1 = pz[r] - bq.y;
                float d0 = fmaf(dx0, dx0, fmaf(dy0, dy0, dz0 * dz0));
                float d1 = fmaf(dx1, dx1, fmaf(dy1, dy1, dz1 * dz1));
                float er0, er1;
                if (SQ) {
                    float e20 = fexp2(ls2n * d0);
                    float e21 = fexp2(ls2n * d1);
                    acc_s[r].x = fmaf(e20, c.x, acc_s[r].x);
                    acc_s[r].y = fmaf(e21, c.y, acc_s[r].y);
                    float e40 = e20 * e20, e41 = e21 * e21;
                    er0 = (e40 * e40) * bq.z;
                    er1 = (e41 * e41) * bq.w;
                } else {
                    // only used for t=8 where ls2n == 0 -> e2 == 1
                    er0 = fexp2(ls2 * d0) * bq.z;
                    er1 = fexp2(ls2 * d1) * bq.w;
                    acc_s[r].x += c.x;
                    acc_s[r].y += c.y;
                }
                acc_a[r].x += er0;
                acc_a[r].y += er1;
                acc_c[r].x = fmaf(er0, fsqrt(d0), acc_c[r].x);
                acc_c[r].y = fmaf(er1, fsqrt(d1), acc_c[r].y);
            }
        }
    }
    float wcost = 0.0f;
#pragma unroll
    for (int r = 0; r < RPW; ++r) {
        float sa = wave_reduce(acc_a[r].x + acc_a[r].y);
        float sc = wave_reduce(acc_c[r].x + acc_c[r].y);
        float ss = wave_reduce(acc_s[r].x + acc_s[r].y);
        if (lane == 0) {
            int idx = b * NPTS + row0 + r;
            float rl = ratioL[idx];
            float rem = fmaxf(0.0f, remainL[idx] - rl * sa);
            remainL[idx] = rem;
            ratioL[idx] = rem / (EMD_EPS + ss);   // next sweep's ratioL
            wcost = fmaf(rl, sc, wcost);
        }
    }
    if (lane == 0) s_cost[wave] = wcost;
    __syncthreads();
    if (tid == 0) {
        float t = s_cost[0] + s_cost[1] + s_cost[2] + s_cost[3];
        cost_part[b * NBLK + blockIdx.x] += t;   // exclusive owner
    }
}

// ---------------------------------------------------------------- level-0 small kernels
__global__ void k_sum_ratioL(const float* __restrict__ ratioL, float* __restrict__ S_L) {
    const int b = blockIdx.x;
    const int tid = threadIdx.x;
    float s = 0.0f;
    for (int i = tid; i < NPTS; i += 256) s += ratioL[b * NPTS + i];
    s = wave_reduce(s);
    __shared__ float sw[4];
    if ((tid & 63) == 0) sw[tid >> 6] = s;
    __syncthreads();
    if (tid == 0) S_L[b] = sw[0] + sw[1] + sw[2] + sw[3];
}

__global__ void k_ratioR_l0(const float* __restrict__ remainR,
                            const float* __restrict__ S_L,
                            float* __restrict__ ratioR) {
    int i = blockIdx.x * blockDim.x + threadIdx.x;
    int b = i >> 12;                       // NPTS = 4096
    float rv = remainR[i];
    float sumr = rv * S_L[b];
    float cons = fminf(rv / (sumr + EMD_EPS), 1.0f);
    ratioR[i] = cons * rv;
}

// level 0 cost pass: e == 1 -> c_k = sum_l ratioR_l*sqrt(d); cost += ratioL_k*c_k
__global__ __launch_bounds__(THREADS, 2) void k_cost_l0(
        const float* __restrict__ xyz1, const float* __restrict__ xyz2,
        const float* __restrict__ ratioL, const float* __restrict__ ratioR,
        float* __restrict__ cost_part) {
    const int b = blockIdx.y;
    const int tid = threadIdx.x;
    const int wave = tid >> 6;
    const int lane = tid & 63;
    const int row0 = blockIdx.x * RPB + wave * RPW;

    const float* x1 = xyz1 + b * 3 * NPTS;
    const float* x2 = xyz2 + b * 3 * NPTS;
    const float2* x2x = (const float2*)(x2);
    const float2* x2y = (const float2*)(x2 + NPTS);
    const float2* x2z = (const float2*)(x2 + 2 * NPTS);
    const float2* wRv = (const float2*)(ratioR + b * NPTS);

    float px[RPW], py[RPW], pz[RPW];
    float2 acc_c[RPW];
#pragma unroll
    for (int r = 0; r < RPW; ++r) {
        px[r] = x1[row0 + r];
        py[r] = x1[NPTS + row0 + r];
        pz[r] = x1[2 * NPTS + row0 + r];
        acc_c[r] = make_float2(0.0f, 0.0f);
    }
    __shared__ float4 sA[TILE / 2];
    __shared__ float4 sB[TILE / 2];
    __shared__ float s_cost[THREADS / 64];

    for (int c0 = 0; c0 < NPTS; c0 += TILE) {
        __syncthreads();
        for (int i = tid; i < TILE / 2; i += THREADS) {
            int e = c0 / 2 + i;
            float2 xx = x2x[e], yy = x2y[e], zz = x2z[e], wr = wRv[e];
            sA[i] = make_float4(xx.x, xx.y, yy.x, yy.y);
            sB[i] = make_float4(zz.x, zz.y, wr.x, wr.y);
        }
        __syncthreads();
#pragma unroll 2
        for (int j = 0; j < TILE / 128; ++j) {
            float4 a = sA[lane + 64 * j];
            float4 bq = sB[lane + 64 * j];
#pragma unroll
            for (int r = 0; r < RPW; ++r) {
                float dx0 = px[r] - a.x, dx1 = px[r] - a.y;
                float dy0 = py[r] - a.z, dy1 = py[r] - a.w;
                float dz0 = pz[r] - bq.x, dz1 = pz[r] - bq.y;
                float d0 = fmaf(dx0, dx0, fmaf(dy0, dy0, dz0 * dz0));
                float d1 = fmaf(dx1, dx1, fmaf(dy1, dy1, dz1 * dz1));
                acc_c[r].x = fmaf(bq.z, fsqrt(d0), acc_c[r].x);
                acc_c[r].y = fmaf(bq.w, fsqrt(d1), acc_c[r].y);
            }
        }
    }
    float wcost = 0.0f;
#pragma unroll
    for (int r = 0; r < RPW; ++r) {
        float sc = wave_reduce(acc_c[r].x + acc_c[r].y);
        if (lane == 0)
            wcost = fmaf(ratioL[b * NPTS + row0 + r], sc, wcost);
    }
    if (lane == 0) s_cost[wave] = wcost;
    __syncthreads();
    if (tid == 0) {
        float t = s_cost[0] + s_cost[1] + s_cost[2] + s_cost[3];
        cost_part[b * NBLK + blockIdx.x] += t;
    }
}

// ---------------------------------------------------------------- finalize
__global__ void k_final(const float* __restrict__ cost_part, float* __restrict__ out) {
    const int tid = threadIdx.x;
    float s = 0.0f;
    for (int i = tid; i < BATCH * NBLK; i += 256) s += cost_part[i];
    s = wave_reduce(s);
    __shared__ float sw[4];
    if ((tid & 63) == 0) sw[tid >> 6] = s;
    __syncthreads();
    if (tid == 0) out[0] = (sw[0] + sw[1] + sw[2] + sw[3]) / ((float)NPTS * (float)BATCH);
}

extern "C" void kernel_launch(void* const* d_in, const int* in_sizes, int n_in,
                              void* d_out, int out_size, void* d_ws, size_t ws_size,
                              hipStream_t stream) {
    const float* xyz1 = (const float*)d_in[0];
    const float* xyz2 = (const float*)d_in[1];
    float* out = (float*)d_out;

    float* ws = (float*)d_ws;
    float* remainL  = ws;                      // B*N
    float* remainR  = ws + 1 * BATCH * NPTS;   // B*N
    float* ratioL   = ws + 2 * BATCH * NPTS;   // B*N
    float* ratioR   = ws + 3 * BATCH * NPTS;   // B*N
    float* cost_part = ws + 4 * BATCH * NPTS;  // B*NBLK
    float* S_L      = cost_part + BATCH * NBLK; // B

    // levels: -(4^j) for j = 7..-1, then 0; premultiplied by log2(e).
    // Consecutive levels differ by exactly 4x -> ls2[t] == 4*ls2[t+1] exactly.
    static const float levels[10] = {
        -16384.0f, -4096.0f, -1024.0f, -256.0f, -64.0f,
        -16.0f, -4.0f, -1.0f, -0.25f, 0.0f};
    float ls2[10];
    for (int t = 0; t < 10; ++t)
        ls2[t] = (float)(levels[t] * 1.4426950408889634);

    dim3 grid(NBLK, BATCH);

    k_init<<<(BATCH * NPTS + 255) / 256, 256, 0, stream>>>(remainL, remainR, cost_part);
    k_ratioL0<<<grid, THREADS, 0, stream>>>(xyz1, xyz2, ratioL, ls2[0]);
    for (int t = 0; t < 8; ++t) {
        k_ratioR<<<grid, THREADS, 0, stream>>>(xyz1, xyz2, ratioL, ratioR, remainR, ls2[t]);
        k_cost_fused<true><<<grid, THREADS, 0, stream>>>(xyz1, xyz2, ratioL, ratioR,
                                                         remainL, remainR, cost_part,
                                                         ls2[t], ls2[t + 1]);
    }
    // t = 8: next level is 0 (no 4x relation) -> direct-exp variant
    k_ratioR<<<grid, THREADS, 0, stream>>>(xyz1, xyz2, ratioL, ratioR, remainR, ls2[8]);
    k_cost_fused<false><<<grid, THREADS, 0, stream>>>(xyz1, xyz2, ratioL, ratioR,
                                                      remainL, remainR, cost_part,
                                                      ls2[8], 0.0f);
    // sweep 9 (level == 0): pass1/pass2 collapse to vector ops
    k_sum_ratioL<<<BATCH, 256, 0, stream>>>(ratioL, S_L);
    k_ratioR_l0<<<(BATCH * NPTS) / 256, 256, 0, stream>>>(remainR, S_L, ratioR);
    k_cost_l0<<<grid, THREADS, 0, stream>>>(xyz1, xyz2, ratioL, ratioR, cost_part);
    k_final<<<1, 256, 0, stream>>>(cost_part, out);
}